// Round 1
// baseline (86.015 us; speedup 1.0000x reference)
//
#include <hip/hip_runtime.h>
#include <math.h>

#define MM 512
#define NN 1024
#define BB 64
#define SS 50

// K1: R[m,b] = Y[b,m] - sum_n A[m,n] * X[n,b]
// block (64 lanes = b, 4 waves = m), grid = MM/4
__global__ __launch_bounds__(256) void k_r(const float* __restrict__ X,
                                           const float* __restrict__ Y,
                                           const float* __restrict__ A,
                                           float* __restrict__ R) {
  const int b = threadIdx.x;
  const int m = blockIdx.x * 4 + threadIdx.y;
  const float* __restrict__ Arow = A + (size_t)m * NN;
  const float* __restrict__ Xb = X + b;
  float a0 = 0.f, a1 = 0.f, a2 = 0.f, a3 = 0.f;
  #pragma unroll 4
  for (int n = 0; n < NN; n += 4) {
    const float4 a4 = *reinterpret_cast<const float4*>(Arow + n);
    a0 = fmaf(a4.x, Xb[(n + 0) * BB], a0);
    a1 = fmaf(a4.y, Xb[(n + 1) * BB], a1);
    a2 = fmaf(a4.z, Xb[(n + 2) * BB], a2);
    a3 = fmaf(a4.w, Xb[(n + 3) * BB], a3);
  }
  R[m * BB + b] = Y[b * MM + m] - ((a0 + a1) + (a2 + a3));
}

// K2: H1[n,b] = X[n,b] + ETA * sum_m A[m,n] * R[m,b]
// block (64 lanes = b, 4 waves = n), grid = NN/4
__global__ __launch_bounds__(256) void k_h1(const float* __restrict__ X,
                                            const float* __restrict__ A,
                                            const float* __restrict__ R,
                                            float* __restrict__ H1) {
  const int b = threadIdx.x;
  const int n = blockIdx.x * 4 + threadIdx.y;
  float a0 = 0.f, a1 = 0.f, a2 = 0.f, a3 = 0.f;
  #pragma unroll 4
  for (int m = 0; m < MM; m += 4) {
    a0 = fmaf(A[(size_t)(m + 0) * NN + n], R[(m + 0) * BB + b], a0);
    a1 = fmaf(A[(size_t)(m + 1) * NN + n], R[(m + 1) * BB + b], a1);
    a2 = fmaf(A[(size_t)(m + 2) * NN + n], R[(m + 2) * BB + b], a2);
    a3 = fmaf(A[(size_t)(m + 3) * NN + n], R[(m + 3) * BB + b], a3);
  }
  const int idx = n * BB + b;
  H1[idx] = fmaf(0.1f, (a0 + a1) + (a2 + a3), X[idx]);
}

// K3: per-batch block. z, c (pairwise L1 distances), 50-way soft top-s
// softmax accumulated per-wave (no block-wide reductions), out = mask * H1.
__global__ __launch_bounds__(1024) void k_mask(const float* __restrict__ H1,
                                               const float* __restrict__ W,
                                               float* __restrict__ out) {
  const int b = blockIdx.x;
  const int n = threadIdx.x;  // 0..1023
  __shared__ float z_s[NN];
  __shared__ float c_s[NN];
  __shared__ float mask_s[NN];

  const float h = H1[n * BB + b];
  const float z = fabsf(W[n] * h);
  z_s[n] = z;
  mask_s[n] = 0.f;
  __syncthreads();

  // c[n] = sum_j |z[n] - z[j]|  -- 8 accumulators for ILP + accuracy
  float ca[8];
  #pragma unroll
  for (int u = 0; u < 8; ++u) ca[u] = 0.f;
  for (int j = 0; j < NN; j += 8) {
    #pragma unroll
    for (int u = 0; u < 8; ++u) ca[u] += fabsf(z - z_s[j + u]);
  }
  const float c = ((ca[0] + ca[1]) + (ca[2] + ca[3])) +
                  ((ca[4] + ca[5]) + (ca[6] + ca[7]));
  c_s[n] = c;
  __syncthreads();

  // Each wave handles s = wave, wave+16, wave+32 (TAU == 1).
  const int wave = n >> 6;
  const int lane = n & 63;
  float zz[16], cc[16], mp[16];
  #pragma unroll
  for (int k = 0; k < 16; ++k) {
    zz[k] = z_s[lane + 64 * k];
    cc[k] = c_s[lane + 64 * k];
    mp[k] = 0.f;
  }
  for (int s = wave; s < SS; s += 16) {
    const float ks = (float)(NN + 1 - 2 * (s + 1));
    float l[16];
    float mx = -INFINITY;
    #pragma unroll
    for (int k = 0; k < 16; ++k) {
      l[k] = fmaf(ks, zz[k], -cc[k]);
      mx = fmaxf(mx, l[k]);
    }
    #pragma unroll
    for (int off = 32; off > 0; off >>= 1)
      mx = fmaxf(mx, __shfl_xor(mx, off, 64));
    float sum = 0.f;
    #pragma unroll
    for (int k = 0; k < 16; ++k) {
      l[k] = __expf(l[k] - mx);
      sum += l[k];
    }
    #pragma unroll
    for (int off = 32; off > 0; off >>= 1)
      sum += __shfl_xor(sum, off, 64);
    const float rs = 1.f / sum;
    #pragma unroll
    for (int k = 0; k < 16; ++k) mp[k] = fmaf(l[k], rs, mp[k]);
  }
  #pragma unroll
  for (int k = 0; k < 16; ++k) atomicAdd(&mask_s[lane + 64 * k], mp[k]);
  __syncthreads();

  out[n * BB + b] = mask_s[n] * h;
}

extern "C" void kernel_launch(void* const* d_in, const int* in_sizes, int n_in,
                              void* d_out, int out_size, void* d_ws, size_t ws_size,
                              hipStream_t stream) {
  const float* X = (const float*)d_in[0];  // (N,B)
  const float* Y = (const float*)d_in[1];  // (B,M)
  const float* A = (const float*)d_in[2];  // (M,N)
  const float* W = (const float*)d_in[3];  // (N,)
  float* out = (float*)d_out;              // (N,B) f32

  float* R = (float*)d_ws;                 // (M,B) = 128 KB
  float* H1 = R + MM * BB;                 // (N,B) = 256 KB

  k_r  <<<dim3(MM / 4), dim3(64, 4), 0, stream>>>(X, Y, A, R);
  k_h1 <<<dim3(NN / 4), dim3(64, 4), 0, stream>>>(X, A, R, H1);
  k_mask<<<dim3(BB), dim3(1024), 0, stream>>>(H1, W, out);
}

// Round 2
// 52.708 us; speedup vs baseline: 1.6319x; 1.6319x over previous
//
#include <hip/hip_runtime.h>
#include <math.h>

#define MM 512
#define NN 1024
#define BB 64
#define SS 50
#define ETA 0.1f

// K1: R[m,b] = Y[b,m] - sum_n A[m,n]*X[n,b]
// grid 128, block (64,4). Block owns 4 m-rows; wave w sums n-chunk w (256 n's);
// partials combined through LDS. X traffic: 256KB per block (32MB total).
__global__ __launch_bounds__(256) void k_r(const float* __restrict__ X,
                                           const float* __restrict__ Y,
                                           const float* __restrict__ A,
                                           float* __restrict__ R) {
  const int l = threadIdx.x;          // batch b
  const int w = threadIdx.y;          // n-chunk
  const int m0 = blockIdx.x * 4;
  __shared__ float part[4][4][BB];    // [m][w][b]
  float acc0 = 0.f, acc1 = 0.f, acc2 = 0.f, acc3 = 0.f;
  const int n0 = w * 256;
  for (int i = 0; i < 256; i += 4) {
    const int n = n0 + i;
    const float x0 = X[(n + 0) * BB + l];
    const float x1 = X[(n + 1) * BB + l];
    const float x2 = X[(n + 2) * BB + l];
    const float x3 = X[(n + 3) * BB + l];
    const float4 a0 = *reinterpret_cast<const float4*>(A + (size_t)(m0 + 0) * NN + n);
    const float4 a1 = *reinterpret_cast<const float4*>(A + (size_t)(m0 + 1) * NN + n);
    const float4 a2 = *reinterpret_cast<const float4*>(A + (size_t)(m0 + 2) * NN + n);
    const float4 a3 = *reinterpret_cast<const float4*>(A + (size_t)(m0 + 3) * NN + n);
    acc0 = fmaf(a0.x, x0, fmaf(a0.y, x1, fmaf(a0.z, x2, fmaf(a0.w, x3, acc0))));
    acc1 = fmaf(a1.x, x0, fmaf(a1.y, x1, fmaf(a1.z, x2, fmaf(a1.w, x3, acc1))));
    acc2 = fmaf(a2.x, x0, fmaf(a2.y, x1, fmaf(a2.z, x2, fmaf(a2.w, x3, acc2))));
    acc3 = fmaf(a3.x, x0, fmaf(a3.y, x1, fmaf(a3.z, x2, fmaf(a3.w, x3, acc3))));
  }
  part[0][w][l] = acc0;
  part[1][w][l] = acc1;
  part[2][w][l] = acc2;
  part[3][w][l] = acc3;
  __syncthreads();
  const float s = (part[w][0][l] + part[w][1][l]) + (part[w][2][l] + part[w][3][l]);
  R[(m0 + w) * BB + l] = Y[l * MM + (m0 + w)] - s;
}

// K2: H1[n,b] = X[n,b] + ETA*sum_m A[m,n]*R[m,b]; also z_t[b,n] = |W[n]*H1[n,b]|.
// grid 256 (16 n-chunks x 16 b-quads), block (64,4): lanes = n (A coalesced),
// waves = b (R wave-uniform broadcast).
__global__ __launch_bounds__(256) void k_h1z(const float* __restrict__ X,
                                             const float* __restrict__ A,
                                             const float* __restrict__ R,
                                             const float* __restrict__ W,
                                             float* __restrict__ H1,
                                             float* __restrict__ z_t) {
  const int l = threadIdx.x;
  const int nc = blockIdx.x & 15;
  const int bq = blockIdx.x >> 4;
  const int n = nc * BB + l;
  const int b = bq * 4 + threadIdx.y;
  float a0 = 0.f, a1 = 0.f, a2 = 0.f, a3 = 0.f;
  for (int m = 0; m < MM; m += 4) {
    a0 = fmaf(A[(size_t)(m + 0) * NN + n], R[(m + 0) * BB + b], a0);
    a1 = fmaf(A[(size_t)(m + 1) * NN + n], R[(m + 1) * BB + b], a1);
    a2 = fmaf(A[(size_t)(m + 2) * NN + n], R[(m + 2) * BB + b], a2);
    a3 = fmaf(A[(size_t)(m + 3) * NN + n], R[(m + 3) * BB + b], a3);
  }
  const float h = fmaf(ETA, (a0 + a1) + (a2 + a3), X[n * BB + b]);
  H1[n * BB + b] = h;
  z_t[b * NN + n] = fabsf(W[n] * h);
}

// K3: partial c. grid 256 (64 batches x 4 j-chunks), block 256.
// Thread owns 4 n's; loops its 256-j chunk via broadcast float4 LDS reads.
// c_part[q][b][n] summed in fixed order by k_sm (deterministic).
__global__ __launch_bounds__(256) void k_c(const float* __restrict__ z_t,
                                           float* __restrict__ c_part) {
  const int b = blockIdx.x >> 2;
  const int q = blockIdx.x & 3;
  const int t = threadIdx.x;
  __shared__ float4 z4[NN / 4];
  z4[t] = reinterpret_cast<const float4*>(z_t + b * NN)[t];
  __syncthreads();
  const float* zs = reinterpret_cast<const float*>(z4);
  const float zn0 = zs[t];
  const float zn1 = zs[t + 256];
  const float zn2 = zs[t + 512];
  const float zn3 = zs[t + 768];
  float c0 = 0.f, c1 = 0.f, c2 = 0.f, c3 = 0.f;
  const float4* zq = z4 + q * 64;
  #pragma unroll 4
  for (int i = 0; i < 64; ++i) {
    const float4 f = zq[i];
    c0 += (fabsf(zn0 - f.x) + fabsf(zn0 - f.y)) + (fabsf(zn0 - f.z) + fabsf(zn0 - f.w));
    c1 += (fabsf(zn1 - f.x) + fabsf(zn1 - f.y)) + (fabsf(zn1 - f.z) + fabsf(zn1 - f.w));
    c2 += (fabsf(zn2 - f.x) + fabsf(zn2 - f.y)) + (fabsf(zn2 - f.z) + fabsf(zn2 - f.w));
    c3 += (fabsf(zn3 - f.x) + fabsf(zn3 - f.y)) + (fabsf(zn3 - f.z) + fabsf(zn3 - f.w));
  }
  float* cp = c_part + q * (BB * NN) + b * NN;
  cp[t] = c0;
  cp[t + 256] = c1;
  cp[t + 512] = c2;
  cp[t + 768] = c3;
}

// K4: softmax + mask + output. grid 64 (one per batch), block 1024.
// Wave w handles s = w, w+16, w+32, (w+48); per-wave partial masks merged
// through LDS in fixed order (no atomics).
__global__ __launch_bounds__(1024) void k_sm(const float* __restrict__ z_t,
                                             const float* __restrict__ c_part,
                                             const float* __restrict__ H1,
                                             float* __restrict__ out) {
  const int b = blockIdx.x;
  const int n = threadIdx.x;
  __shared__ float z_s[NN];
  __shared__ float c_s[NN];
  __shared__ float mpart[16][NN];

  const float z = z_t[b * NN + n];
  const int ci = b * NN + n;
  const float c = (c_part[ci] + c_part[ci + BB * NN]) +
                  (c_part[ci + 2 * BB * NN] + c_part[ci + 3 * BB * NN]);
  z_s[n] = z;
  c_s[n] = c;
  __syncthreads();

  const int w = n >> 6;
  const int lane = n & 63;
  float zz[16], cc[16], mp[16];
  #pragma unroll
  for (int k = 0; k < 16; ++k) {
    zz[k] = z_s[lane + 64 * k];
    cc[k] = c_s[lane + 64 * k];
    mp[k] = 0.f;
  }
  for (int s = w; s < SS; s += 16) {
    const float ks = (float)(NN + 1 - 2 * (s + 1));
    float l[16];
    float mx = -INFINITY;
    #pragma unroll
    for (int k = 0; k < 16; ++k) {
      l[k] = fmaf(ks, zz[k], -cc[k]);
      mx = fmaxf(mx, l[k]);
    }
    #pragma unroll
    for (int off = 32; off > 0; off >>= 1)
      mx = fmaxf(mx, __shfl_xor(mx, off, 64));
    float sum = 0.f;
    #pragma unroll
    for (int k = 0; k < 16; ++k) {
      l[k] = __expf(l[k] - mx);
      sum += l[k];
    }
    #pragma unroll
    for (int off = 32; off > 0; off >>= 1)
      sum += __shfl_xor(sum, off, 64);
    const float rs = 1.f / sum;
    #pragma unroll
    for (int k = 0; k < 16; ++k) mp[k] = fmaf(l[k], rs, mp[k]);
  }
  #pragma unroll
  for (int k = 0; k < 16; ++k) mpart[w][lane + 64 * k] = mp[k];
  __syncthreads();

  float mask = 0.f;
  #pragma unroll
  for (int u = 0; u < 16; ++u) mask += mpart[u][n];
  out[n * BB + b] = mask * H1[n * BB + b];
}

extern "C" void kernel_launch(void* const* d_in, const int* in_sizes, int n_in,
                              void* d_out, int out_size, void* d_ws, size_t ws_size,
                              hipStream_t stream) {
  const float* X = (const float*)d_in[0];  // (N,B)
  const float* Y = (const float*)d_in[1];  // (B,M)
  const float* A = (const float*)d_in[2];  // (M,N)
  const float* W = (const float*)d_in[3];  // (N,)
  float* out = (float*)d_out;              // (N,B)

  float* H1 = (float*)d_ws;                // 65536 f
  float* z_t = H1 + NN * BB;               // 65536 f
  float* c_part = z_t + NN * BB;           // 262144 f
  float* R = c_part;                       // 32768 f, dead before k_c writes

  k_r   <<<dim3(MM / 4), dim3(64, 4), 0, stream>>>(X, Y, A, R);
  k_h1z <<<dim3(256), dim3(64, 4), 0, stream>>>(X, A, R, W, H1, z_t);
  k_c   <<<dim3(BB * 4), dim3(256), 0, stream>>>(z_t, c_part);
  k_sm  <<<dim3(BB), dim3(1024), 0, stream>>>(z_t, c_part, H1, out);
}

// Round 3
// 47.316 us; speedup vs baseline: 1.8179x; 1.1140x over previous
//
#include <hip/hip_runtime.h>
#include <math.h>

#define MM 512
#define NN 1024
#define BB 64
#define SS 50
#define ETA 0.1f

// K1: R[m,b] = Y[b,m] - sum_n A[m,n]*X[n,b]
// grid 256, block (64,8). Block owns 2 m-rows; wave w sums n-chunk w (128 n);
// 8-way LDS tree reduce. 2 waves/SIMD; short per-wave chains.
__global__ __launch_bounds__(512) void k_r(const float* __restrict__ X,
                                           const float* __restrict__ Y,
                                           const float* __restrict__ A,
                                           float* __restrict__ R) {
  const int l = threadIdx.x;          // batch b
  const int w = threadIdx.y;          // n-chunk 0..7
  const int m0 = blockIdx.x * 2;
  __shared__ float part[8][2][BB];
  const float* __restrict__ Xp = X + w * 128 * BB + l;
  const float* __restrict__ A0 = A + (size_t)m0 * NN + w * 128;
  const float* __restrict__ A1 = A0 + NN;
  float r0a = 0.f, r0b = 0.f, r1a = 0.f, r1b = 0.f;
  #pragma unroll 4
  for (int i = 0; i < 128; i += 4) {
    const float x0 = Xp[(i + 0) * BB];
    const float x1 = Xp[(i + 1) * BB];
    const float x2 = Xp[(i + 2) * BB];
    const float x3 = Xp[(i + 3) * BB];
    const float4 a0 = *reinterpret_cast<const float4*>(A0 + i);
    const float4 a1 = *reinterpret_cast<const float4*>(A1 + i);
    r0a = fmaf(a0.x, x0, fmaf(a0.y, x1, r0a));
    r0b = fmaf(a0.z, x2, fmaf(a0.w, x3, r0b));
    r1a = fmaf(a1.x, x0, fmaf(a1.y, x1, r1a));
    r1b = fmaf(a1.z, x2, fmaf(a1.w, x3, r1b));
  }
  part[w][0][l] = r0a + r0b;
  part[w][1][l] = r1a + r1b;
  __syncthreads();
  if (w < 2) {
    const float s =
        ((part[0][w][l] + part[1][w][l]) + (part[2][w][l] + part[3][w][l])) +
        ((part[4][w][l] + part[5][w][l]) + (part[6][w][l] + part[7][w][l]));
    R[(m0 + w) * BB + l] = Y[l * MM + (m0 + w)] - s;
  }
}

// K2: H1_t[b,n] = X[n,b] + ETA*sum_m A[m,n]*R[m,b]; z_t[b,n] = |W[n]*H1|.
// grid 256 (16 nc x 16 bq), block (64,4): lanes = n (A coalesced, L1-reuse
// across the 4 b-waves), 8 accumulators for deep load pipelining.
__global__ __launch_bounds__(256) void k_h1z(const float* __restrict__ X,
                                             const float* __restrict__ A,
                                             const float* __restrict__ R,
                                             const float* __restrict__ W,
                                             float* __restrict__ H1_t,
                                             float* __restrict__ z_t) {
  const int l = threadIdx.x;
  const int nc = blockIdx.x & 15;
  const int bq = blockIdx.x >> 4;
  const int n = nc * BB + l;
  const int b = bq * 4 + threadIdx.y;
  const float* __restrict__ Ap = A + n;
  const float* __restrict__ Rp = R + b;
  float a0 = 0.f, a1 = 0.f, a2 = 0.f, a3 = 0.f;
  float a4 = 0.f, a5 = 0.f, a6 = 0.f, a7 = 0.f;
  for (int m = 0; m < MM; m += 8) {
    a0 = fmaf(Ap[(size_t)(m + 0) * NN], Rp[(m + 0) * BB], a0);
    a1 = fmaf(Ap[(size_t)(m + 1) * NN], Rp[(m + 1) * BB], a1);
    a2 = fmaf(Ap[(size_t)(m + 2) * NN], Rp[(m + 2) * BB], a2);
    a3 = fmaf(Ap[(size_t)(m + 3) * NN], Rp[(m + 3) * BB], a3);
    a4 = fmaf(Ap[(size_t)(m + 4) * NN], Rp[(m + 4) * BB], a4);
    a5 = fmaf(Ap[(size_t)(m + 5) * NN], Rp[(m + 5) * BB], a5);
    a6 = fmaf(Ap[(size_t)(m + 6) * NN], Rp[(m + 6) * BB], a6);
    a7 = fmaf(Ap[(size_t)(m + 7) * NN], Rp[(m + 7) * BB], a7);
  }
  const float s = ((a0 + a1) + (a2 + a3)) + ((a4 + a5) + (a6 + a7));
  const float h = fmaf(ETA, s, X[n * BB + b]);
  H1_t[b * NN + n] = h;
  z_t[b * NN + n] = fabsf(W[n] * h);
}

// K3: partial c. grid 256 (64 b x 4 j-chunks), block 256.
// Thread owns 4 n's; scans its 256-j chunk via broadcast float4 LDS reads.
__global__ __launch_bounds__(256) void k_c(const float* __restrict__ z_t,
                                           float* __restrict__ c_part) {
  const int b = blockIdx.x >> 2;
  const int q = blockIdx.x & 3;
  const int t = threadIdx.x;
  __shared__ __align__(16) float4 z4[NN / 4];
  z4[t] = reinterpret_cast<const float4*>(z_t + b * NN)[t];
  __syncthreads();
  const float* zs = reinterpret_cast<const float*>(z4);
  const float zn0 = zs[t];
  const float zn1 = zs[t + 256];
  const float zn2 = zs[t + 512];
  const float zn3 = zs[t + 768];
  float c0 = 0.f, c1 = 0.f, c2 = 0.f, c3 = 0.f;
  const float4* zq = z4 + q * 64;
  #pragma unroll 4
  for (int i = 0; i < 64; ++i) {
    const float4 f = zq[i];
    c0 += (fabsf(zn0 - f.x) + fabsf(zn0 - f.y)) + (fabsf(zn0 - f.z) + fabsf(zn0 - f.w));
    c1 += (fabsf(zn1 - f.x) + fabsf(zn1 - f.y)) + (fabsf(zn1 - f.z) + fabsf(zn1 - f.w));
    c2 += (fabsf(zn2 - f.x) + fabsf(zn2 - f.y)) + (fabsf(zn2 - f.z) + fabsf(zn2 - f.w));
    c3 += (fabsf(zn3 - f.x) + fabsf(zn3 - f.y)) + (fabsf(zn3 - f.z) + fabsf(zn3 - f.w));
  }
  float* cp = c_part + q * (BB * NN) + b * NN;
  cp[t] = c0;
  cp[t + 256] = c1;
  cp[t + 512] = c2;
  cp[t + 768] = c3;
}

// K4: softmax + mask + out. grid 64, block 1024. Lane owns 16 CONSECUTIVE n
// (b128 LDS traffic); wave w handles s = w, w+16, w+32(, w+48).
__global__ __launch_bounds__(1024) void k_sm(const float* __restrict__ z_t,
                                             const float* __restrict__ c_part,
                                             const float* __restrict__ H1_t,
                                             float* __restrict__ out) {
  const int b = blockIdx.x;
  const int t = threadIdx.x;
  __shared__ __align__(16) float z_s[NN];
  __shared__ __align__(16) float c_s[NN];
  __shared__ __align__(16) float mpart[16][NN];

  z_s[t] = z_t[b * NN + t];
  const int ci = b * NN + t;
  c_s[t] = (c_part[ci] + c_part[ci + BB * NN]) +
           (c_part[ci + 2 * BB * NN] + c_part[ci + 3 * BB * NN]);
  const float h = H1_t[b * NN + t];
  __syncthreads();

  const int w = t >> 6;
  const int lane = t & 63;
  const int nb = lane * 16;
  float zz[16], cc[16], mp[16];
  #pragma unroll
  for (int k = 0; k < 4; ++k) {
    reinterpret_cast<float4*>(zz)[k] = reinterpret_cast<const float4*>(z_s + nb)[k];
    reinterpret_cast<float4*>(cc)[k] = reinterpret_cast<const float4*>(c_s + nb)[k];
  }
  #pragma unroll
  for (int k = 0; k < 16; ++k) mp[k] = 0.f;

  for (int s = w; s < SS; s += 16) {
    const float ks = (float)(NN + 1 - 2 * (s + 1));
    float lg[16];
    float mx = -INFINITY;
    #pragma unroll
    for (int k = 0; k < 16; ++k) {
      lg[k] = fmaf(ks, zz[k], -cc[k]);
      mx = fmaxf(mx, lg[k]);
    }
    #pragma unroll
    for (int off = 32; off > 0; off >>= 1)
      mx = fmaxf(mx, __shfl_xor(mx, off, 64));
    float sum = 0.f;
    #pragma unroll
    for (int k = 0; k < 16; ++k) {
      lg[k] = __expf(lg[k] - mx);
      sum += lg[k];
    }
    #pragma unroll
    for (int off = 32; off > 0; off >>= 1)
      sum += __shfl_xor(sum, off, 64);
    const float rs = 1.f / sum;
    #pragma unroll
    for (int k = 0; k < 16; ++k) mp[k] = fmaf(lg[k], rs, mp[k]);
  }
  #pragma unroll
  for (int k = 0; k < 4; ++k)
    reinterpret_cast<float4*>(&mpart[w][nb])[k] = reinterpret_cast<float4*>(mp)[k];
  __syncthreads();

  float mask = 0.f;
  #pragma unroll
  for (int u = 0; u < 16; ++u) mask += mpart[u][t];
  out[t * BB + b] = mask * h;
}

extern "C" void kernel_launch(void* const* d_in, const int* in_sizes, int n_in,
                              void* d_out, int out_size, void* d_ws, size_t ws_size,
                              hipStream_t stream) {
  const float* X = (const float*)d_in[0];  // (N,B)
  const float* Y = (const float*)d_in[1];  // (B,M)
  const float* A = (const float*)d_in[2];  // (M,N)
  const float* W = (const float*)d_in[3];  // (N,)
  float* out = (float*)d_out;              // (N,B)

  float* R = (float*)d_ws;                 // 32768 f
  float* z_t = R + MM * BB;                // 65536 f
  float* H1_t = z_t + NN * BB;             // 65536 f
  float* c_part = H1_t + NN * BB;          // 262144 f

  k_r   <<<dim3(MM / 2), dim3(64, 8), 0, stream>>>(X, Y, A, R);
  k_h1z <<<dim3(256), dim3(64, 4), 0, stream>>>(X, A, R, W, H1_t, z_t);
  k_c   <<<dim3(BB * 4), dim3(256), 0, stream>>>(z_t, c_part);
  k_sm  <<<dim3(BB), dim3(1024), 0, stream>>>(z_t, c_part, H1_t, out);
}

// Round 4
// 37.126 us; speedup vs baseline: 2.3168x; 1.2745x over previous
//
#include <hip/hip_runtime.h>
#include <math.h>

#define MM 512
#define NN 1024
#define BB 64
#define SS 50
#define ETA 0.1f

// K1: R[m,b] = Y[b,m] - sum_n A[m,n]*X[n,b]
// grid 256, block (64,8). Block owns 2 m-rows; wave w sums n-chunk w (128 n);
// 8-way LDS tree reduce. 2 waves/SIMD.
__global__ __launch_bounds__(512) void k_r(const float* __restrict__ X,
                                           const float* __restrict__ Y,
                                           const float* __restrict__ A,
                                           float* __restrict__ R) {
  const int l = threadIdx.x;          // batch b
  const int w = threadIdx.y;          // n-chunk 0..7
  const int m0 = blockIdx.x * 2;
  __shared__ float part[8][2][BB];
  const float* __restrict__ Xp = X + w * 128 * BB + l;
  const float* __restrict__ A0 = A + (size_t)m0 * NN + w * 128;
  const float* __restrict__ A1 = A0 + NN;
  float r0a = 0.f, r0b = 0.f, r1a = 0.f, r1b = 0.f;
  #pragma unroll 8
  for (int i = 0; i < 128; i += 4) {
    const float x0 = Xp[(i + 0) * BB];
    const float x1 = Xp[(i + 1) * BB];
    const float x2 = Xp[(i + 2) * BB];
    const float x3 = Xp[(i + 3) * BB];
    const float4 a0 = *reinterpret_cast<const float4*>(A0 + i);
    const float4 a1 = *reinterpret_cast<const float4*>(A1 + i);
    r0a = fmaf(a0.x, x0, fmaf(a0.y, x1, r0a));
    r0b = fmaf(a0.z, x2, fmaf(a0.w, x3, r0b));
    r1a = fmaf(a1.x, x0, fmaf(a1.y, x1, r1a));
    r1b = fmaf(a1.z, x2, fmaf(a1.w, x3, r1b));
  }
  part[w][0][l] = r0a + r0b;
  part[w][1][l] = r1a + r1b;
  __syncthreads();
  if (w < 2) {
    const float s =
        ((part[0][w][l] + part[1][w][l]) + (part[2][w][l] + part[3][w][l])) +
        ((part[4][w][l] + part[5][w][l]) + (part[6][w][l] + part[7][w][l]));
    R[(m0 + w) * BB + l] = Y[l * MM + (m0 + w)] - s;
  }
}

// K2: H1_t[b,n] = X[n,b] + ETA*sum_m A[m,n]*R[m,b]; z_t[b,n] = |W[n]*H1|.
// grid 256 (8 nc x 32 b-pairs), block (64,8): wave = (b_local, m-chunk of 128).
// Lane owns float2 of n (A loads coalesced 512B, 2 fma/load); R wave-uniform.
// 4 m-partials tree-combined in LDS. 2 waves/SIMD, ~32 loads in flight/SIMD.
__global__ __launch_bounds__(512) void k_h1z(const float* __restrict__ X,
                                             const float* __restrict__ A,
                                             const float* __restrict__ R,
                                             const float* __restrict__ W,
                                             float* __restrict__ H1_t,
                                             float* __restrict__ z_t) {
  const int l = threadIdx.x;
  const int w = threadIdx.y;          // 0..7
  const int b_l = w >> 2;             // 0..1
  const int mc = w & 3;               // 0..3
  const int nc = blockIdx.x & 7;
  const int bp = blockIdx.x >> 3;     // 0..31
  const int b = bp * 2 + b_l;
  const int n0 = nc * 128;
  __shared__ float part[2][4][128];
  const float* __restrict__ Ap = A + (size_t)(mc * 128) * NN + n0 + l * 2;
  const float* __restrict__ Rp = R + (size_t)(mc * 128) * BB + b;
  float s0 = 0.f, s1 = 0.f, s2 = 0.f, s3 = 0.f;
  float t0 = 0.f, t1 = 0.f, t2 = 0.f, t3 = 0.f;
  #pragma unroll 2
  for (int i = 0; i < 128; i += 4) {
    const float2 a0 = *reinterpret_cast<const float2*>(Ap + (size_t)(i + 0) * NN);
    const float2 a1 = *reinterpret_cast<const float2*>(Ap + (size_t)(i + 1) * NN);
    const float2 a2 = *reinterpret_cast<const float2*>(Ap + (size_t)(i + 2) * NN);
    const float2 a3 = *reinterpret_cast<const float2*>(Ap + (size_t)(i + 3) * NN);
    const float r0 = Rp[(i + 0) * BB];
    const float r1 = Rp[(i + 1) * BB];
    const float r2 = Rp[(i + 2) * BB];
    const float r3 = Rp[(i + 3) * BB];
    s0 = fmaf(a0.x, r0, s0); t0 = fmaf(a0.y, r0, t0);
    s1 = fmaf(a1.x, r1, s1); t1 = fmaf(a1.y, r1, t1);
    s2 = fmaf(a2.x, r2, s2); t2 = fmaf(a2.y, r2, t2);
    s3 = fmaf(a3.x, r3, s3); t3 = fmaf(a3.y, r3, t3);
  }
  part[b_l][mc][l * 2 + 0] = (s0 + s1) + (s2 + s3);
  part[b_l][mc][l * 2 + 1] = (t0 + t1) + (t2 + t3);
  __syncthreads();
  const int tid = w * 64 + l;
  if (tid < 256) {
    const int bl2 = tid >> 7;
    const int nn = tid & 127;
    const int bb = bp * 2 + bl2;
    const int n = n0 + nn;
    const float s = (part[bl2][0][nn] + part[bl2][1][nn]) +
                    (part[bl2][2][nn] + part[bl2][3][nn]);
    const float h = fmaf(ETA, s, X[n * BB + bb]);
    H1_t[bb * NN + n] = h;
    z_t[bb * NN + n] = fabsf(W[n] * h);
  }
}

// K3: partial c. grid 512 (64 b x 8 j-chunks of 128), block 256.
// Thread owns 4 n (t, t+256, t+512, t+768); scans its j-chunk via broadcast
// float4 LDS reads. 2 blocks/CU.
__global__ __launch_bounds__(256) void k_c(const float* __restrict__ z_t,
                                           float* __restrict__ c_part) {
  const int b = blockIdx.x >> 3;
  const int q = blockIdx.x & 7;
  const int t = threadIdx.x;
  __shared__ __align__(16) float4 z4[NN / 4];
  z4[t] = reinterpret_cast<const float4*>(z_t + b * NN)[t];
  __syncthreads();
  const float* zs = reinterpret_cast<const float*>(z4);
  const float zn0 = zs[t];
  const float zn1 = zs[t + 256];
  const float zn2 = zs[t + 512];
  const float zn3 = zs[t + 768];
  float c0 = 0.f, c1 = 0.f, c2 = 0.f, c3 = 0.f;
  const float4* zq = z4 + q * 32;
  #pragma unroll 4
  for (int i = 0; i < 32; ++i) {
    const float4 f = zq[i];
    c0 += (fabsf(zn0 - f.x) + fabsf(zn0 - f.y)) + (fabsf(zn0 - f.z) + fabsf(zn0 - f.w));
    c1 += (fabsf(zn1 - f.x) + fabsf(zn1 - f.y)) + (fabsf(zn1 - f.z) + fabsf(zn1 - f.w));
    c2 += (fabsf(zn2 - f.x) + fabsf(zn2 - f.y)) + (fabsf(zn2 - f.z) + fabsf(zn2 - f.w));
    c3 += (fabsf(zn3 - f.x) + fabsf(zn3 - f.y)) + (fabsf(zn3 - f.z) + fabsf(zn3 - f.w));
  }
  float* cp = c_part + q * (BB * NN) + b * NN;
  cp[t] = c0;
  cp[t + 256] = c1;
  cp[t + 512] = c2;
  cp[t + 768] = c3;
}

// K4: softmax + mask + out. grid 64, block 1024. Lane owns 16 INTERLEAVED n
// (lane + 64k): zc float2 reads at 8B stride (2-way = free), mpart scalar
// (4B stride, conflict-free). Wave w handles s = w, w+16, w+32(, w+48).
__global__ __launch_bounds__(1024) void k_sm(const float* __restrict__ z_t,
                                             const float* __restrict__ c_part,
                                             const float* __restrict__ H1_t,
                                             float* __restrict__ out) {
  const int b = blockIdx.x;
  const int t = threadIdx.x;
  __shared__ __align__(16) float2 zc_s[NN];
  __shared__ float mpart[16][NN];

  const float z = z_t[b * NN + t];
  const int ci = b * NN + t;
  const int BN = BB * NN;
  const float c = ((c_part[ci] + c_part[ci + BN]) +
                   (c_part[ci + 2 * BN] + c_part[ci + 3 * BN])) +
                  ((c_part[ci + 4 * BN] + c_part[ci + 5 * BN]) +
                   (c_part[ci + 6 * BN] + c_part[ci + 7 * BN]));
  zc_s[t] = make_float2(z, c);
  const float h = H1_t[b * NN + t];
  __syncthreads();

  const int w = t >> 6;
  const int lane = t & 63;
  float zz[16], cc[16], mp[16];
  #pragma unroll
  for (int k = 0; k < 16; ++k) {
    const float2 v = zc_s[lane + 64 * k];
    zz[k] = v.x;
    cc[k] = v.y;
    mp[k] = 0.f;
  }

  for (int s = w; s < SS; s += 16) {
    const float ks = (float)(NN + 1 - 2 * (s + 1));
    float lg[16];
    float mx = -INFINITY;
    #pragma unroll
    for (int k = 0; k < 16; ++k) {
      lg[k] = fmaf(ks, zz[k], -cc[k]);
      mx = fmaxf(mx, lg[k]);
    }
    #pragma unroll
    for (int off = 32; off > 0; off >>= 1)
      mx = fmaxf(mx, __shfl_xor(mx, off, 64));
    float sum = 0.f;
    #pragma unroll
    for (int k = 0; k < 16; ++k) {
      lg[k] = __expf(lg[k] - mx);
      sum += lg[k];
    }
    #pragma unroll
    for (int off = 32; off > 0; off >>= 1)
      sum += __shfl_xor(sum, off, 64);
    const float rs = 1.f / sum;
    #pragma unroll
    for (int k = 0; k < 16; ++k) mp[k] = fmaf(lg[k], rs, mp[k]);
  }
  #pragma unroll
  for (int k = 0; k < 16; ++k) mpart[w][lane + 64 * k] = mp[k];
  __syncthreads();

  float mask = 0.f;
  #pragma unroll
  for (int u = 0; u < 16; ++u) mask += mpart[u][t];
  out[t * BB + b] = mask * h;
}

extern "C" void kernel_launch(void* const* d_in, const int* in_sizes, int n_in,
                              void* d_out, int out_size, void* d_ws, size_t ws_size,
                              hipStream_t stream) {
  const float* X = (const float*)d_in[0];  // (N,B)
  const float* Y = (const float*)d_in[1];  // (B,M)
  const float* A = (const float*)d_in[2];  // (M,N)
  const float* W = (const float*)d_in[3];  // (N,)
  float* out = (float*)d_out;              // (N,B)

  float* R = (float*)d_ws;                 // 32768 f
  float* z_t = R + MM * BB;                // 65536 f
  float* H1_t = z_t + NN * BB;             // 65536 f
  float* c_part = H1_t + NN * BB;          // 8*65536 f

  k_r   <<<dim3(MM / 2), dim3(64, 8), 0, stream>>>(X, Y, A, R);
  k_h1z <<<dim3(256), dim3(64, 8), 0, stream>>>(X, A, R, W, H1_t, z_t);
  k_c   <<<dim3(BB * 8), dim3(256), 0, stream>>>(z_t, c_part);
  k_sm  <<<dim3(BB), dim3(1024), 0, stream>>>(z_t, c_part, H1_t, out);
}